// Round 8
// baseline (1563.046 us; speedup 1.0000x reference)
//
#include <hip/hip_runtime.h>

#define T_STEPS 24
#define BB 64
#define I_DIM 128
#define HH 256
#define RR 64
#define HR 320   // H + R
#define NREG_TE 7
#define NLDS_TE 9   // tE chunks 7..15 live in LDS

// ---------------- init: per-(i,j) constants, chunk-major swizzled ----------
// Element (i,j): c=j>>4, qq=(j>>2)&3, e=j&3. Owner thread t0=i*4+qq processes
// chunk c as float4 #(c*1024+t0). Swizzled flat index = (c*1024+i*4+qq)*4+e.
__global__ __launch_bounds__(256) void k_init_const(
    const float* __restrict__ alpha, const float* __restrict__ tau_U,
    const float* __restrict__ tau_E, const float* __restrict__ tau_v,
    const float* __restrict__ h2h_w,
    float* __restrict__ ra, float* __restrict__ sU, float* __restrict__ sE,
    float* __restrict__ hi, float* __restrict__ lo, float* __restrict__ sv)
{
    int idx = blockIdx.x * 256 + threadIdx.x;
    if (idx >= HH * HH) return;
    int i = idx >> 8, j = idx & 255;
    int c = j >> 4, qq = (j >> 2) & 3, e = j & 3;
    int sidx = (c * 1024 + i * 4 + qq) * 4 + e;
    float a = alpha[idx]; a = a > 0.f ? a : 0.f;
    ra[sidx] = a;
    sU[sidx] = 1.f / (1.f + expf(-tau_U[idx]));
    sE[sidx] = 1.f / (1.f + expf(-tau_E[idx]));
    float wv = h2h_w[idx];
    float inv = 1.f / (a + 1e-8f);
    float hi_ = 1.0f - wv; hi_ = hi_ > 0.f ? hi_ : 0.f;
    float lo_ = 1.0f + wv; lo_ = lo_ > 0.f ? lo_ : 0.f;
    hi[sidx] = hi_ * inv;
    lo[sidx] = -lo_ * inv;
    if (idx < HH) sv[idx] = 1.f / (1.f + expf(-tau_v[idx]));
}

// ---------------- init: Wx = LN(x @ x2h_w.T + b) for all T ----------------
__global__ __launch_bounds__(HR) void k_wx(
    const float* __restrict__ x, const float* __restrict__ w,
    const float* __restrict__ bias,
    const float* __restrict__ g, const float* __restrict__ be,
    float* __restrict__ Wx)
{
    __shared__ float xs[I_DIM];
    __shared__ float rs[5], rs2[5];
    int row = blockIdx.x;
    int p = threadIdx.x;
    if (p < I_DIM) xs[p] = x[(size_t)row * I_DIM + p];
    __syncthreads();
    const float* wr = w + (size_t)p * I_DIM;
    float acc = bias[p];
    #pragma unroll 8
    for (int k = 0; k < I_DIM; k += 4)
        acc += wr[k]*xs[k] + wr[k+1]*xs[k+1] + wr[k+2]*xs[k+2] + wr[k+3]*xs[k+3];
    float s = acc, s2 = acc * acc;
    int lane = p & 63, wv = p >> 6;
    for (int off = 32; off > 0; off >>= 1) { s += __shfl_down(s, off); s2 += __shfl_down(s2, off); }
    if (lane == 0) { rs[wv] = s; rs2[wv] = s2; }
    __syncthreads();
    float sum = 0.f, sum2 = 0.f;
    #pragma unroll
    for (int q = 0; q < 5; q++) { sum += rs[q]; sum2 += rs2[q]; }
    float mu = sum * (1.f / HR);
    float rstd = rsqrtf(sum2 * (1.f / HR) - mu * mu + 1e-5f);
    Wx[(size_t)row * HR + p] = (acc - mu) * rstd * g[p] + be[p];
}

// ---------------- persistent per-batch scan: 64 blocks x 1024 threads ------
// Thread t0: row i=t0>>2, qq=t0&3; owns j = c*16+qq*4+{0..3}, c=0..15.
// dU: 16 f4 chunks in regs. tE: chunks 0..6 regs, 7..15 in LDS.
// __launch_bounds__(1024, 4): min 4 waves/EU -> VGPR cap 128 (state = 92).
__global__ __launch_bounds__(1024, 4) void k_batch(
    const float* __restrict__ dU0, const float* __restrict__ tE0,
    const float* __restrict__ h0, const float* __restrict__ v0,
    const float* __restrict__ te0,
    const float* __restrict__ Wx,      // (T,B,HR)
    const float* __restrict__ h2h_w, const float* __restrict__ h2h_b,
    const float* __restrict__ lnh_g, const float* __restrict__ lnh_b,
    const float* __restrict__ sv_g,
    const float* __restrict__ mod2h,   // (H,R) natural layout
    const float* __restrict__ raS, const float* __restrict__ sUS,
    const float* __restrict__ sES, const float* __restrict__ hiS,
    const float* __restrict__ loS,     // swizzled chunk-major
    float* __restrict__ o_v, float* __restrict__ o_h, float* __restrict__ o_dU,
    float* __restrict__ o_te, float* __restrict__ o_tE, float* __restrict__ o_out)
{
    __shared__ __align__(16) float4 tE_lds[NLDS_TE * 1024];   // 147456 B
    __shared__ __align__(16) float sh_h[2][HH];
    __shared__ __align__(16) float sh_te[2][HH];
    __shared__ float sh_v[HH];
    __shared__ float sh_s[HH];
    __shared__ __align__(16) float sh_modin[RR];
    __shared__ float sh_red[5], sh_red2[5];

    const int b   = blockIdx.x;
    const int t0  = threadIdx.x;
    const int i   = t0 >> 2;
    const int qq  = t0 & 3;
    const int wv  = t0 >> 6;
    const int lane = t0 & 63;

    const float4* raS4 = (const float4*)raS;
    const float4* sUS4 = (const float4*)sUS;
    const float4* sES4 = (const float4*)sES;
    const float4* hiS4 = (const float4*)hiS;
    const float4* loS4 = (const float4*)loS;
    const float4* m2h4 = (const float4*)mod2h;

    // ---- load persistent state ----
    const size_t sbase = ((size_t)b * HH + i) * 64 + qq;   // f4 units; chunk c at +c*4
    const float4* dU0v = (const float4*)dU0;
    const float4* tE0v = (const float4*)tE0;
    float4 duR[16];
    float4 teR[NREG_TE];
    #pragma unroll
    for (int c = 0; c < 16; ++c) duR[c] = dU0v[sbase + c * 4];
    #pragma unroll
    for (int c = 0; c < NREG_TE; ++c) teR[c] = tE0v[sbase + c * 4];
    #pragma unroll
    for (int c2 = 0; c2 < NLDS_TE; ++c2)
        tE_lds[c2 * 1024 + t0] = tE0v[sbase + (NREG_TE + c2) * 4];

    if (t0 < HH) {
        sh_h[0][t0]  = h0[(size_t)b * HH + t0];
        sh_te[0][t0] = te0[(size_t)b * HH + t0];
        sh_v[t0]     = v0[(size_t)b * HH + t0];
    }
    __syncthreads();

    // ---- initial s = einsum(ra*dU0, h0) ----
    {
        float acc = 0.f;
        #pragma unroll
        for (int c = 0; c < 16; ++c) {
            const float4 raV = raS4[c * 1024 + t0];
            const int j0 = c * 16 + qq * 4;
            const float4 h4 = *(const float4*)&sh_h[0][j0];
            const float4 d = duR[c];
            acc += raV.x*d.x*h4.x + raV.y*d.y*h4.y + raV.z*d.z*h4.z + raV.w*d.w*h4.w;
        }
        acc += __shfl_xor(acc, 1, 4);
        acc += __shfl_xor(acc, 2, 4);
        if (qq == 0) sh_s[i] = acc;
    }
    __syncthreads();

    #pragma unroll 1
    for (int t = 0; t < T_STEPS; ++t) {
        const int cur = t & 1, nxt = cur ^ 1;

        // ---- A1: Wh_pre matvec (threads 0..319, one row each) ----
        float pre = 0.f;
        if (t0 < HR) {
            const float4* wr4 = (const float4*)(h2h_w + (size_t)t0 * HH);
            float a0 = h2h_b[t0], a1 = 0.f;
            #pragma unroll 8
            for (int k = 0; k < 64; k += 2) {
                float4 w0 = wr4[k],     w1 = wr4[k+1];
                float4 h0v = *(const float4*)&sh_h[cur][k << 2];
                float4 h1v = *(const float4*)&sh_h[cur][(k+1) << 2];
                a0 += w0.x*h0v.x + w0.y*h0v.y + w0.z*h0v.z + w0.w*h0v.w;
                a1 += w1.x*h1v.x + w1.y*h1v.y + w1.z*h1v.z + w1.w*h1v.w;
            }
            pre = a0 + a1;
            float s = pre, s2 = pre * pre;
            #pragma unroll
            for (int off = 32; off > 0; off >>= 1) {
                s += __shfl_down(s, off); s2 += __shfl_down(s2, off);
            }
            if (lane == 0) { sh_red[wv] = s; sh_red2[wv] = s2; }
        }
        __syncthreads();

        // ---- A2: LN + v/nh/nte/modin ----
        {
            float sum = 0.f, sum2 = 0.f;
            #pragma unroll
            for (int q = 0; q < 5; ++q) { sum += sh_red[q]; sum2 += sh_red2[q]; }
            float mu = sum * (1.f / HR);
            float rstd = rsqrtf(sum2 * (1.f / HR) - mu * mu + 1e-5f);
            if (t0 < HR) {
                float wh = (pre - mu) * rstd * lnh_g[t0] + lnh_b[t0];
                float wx = Wx[((size_t)t * BB + b) * HR + t0];
                if (t0 < HH) {
                    float svp = sv_g[t0];
                    float dv = wx + wh + sh_s[t0];
                    float vnew = (1.f - svp) * sh_v[t0] + svp * dv;
                    sh_v[t0] = vnew;
                    float nh = vnew > 0.f ? vnew : 0.f;
                    sh_h[nxt][t0] = nh;
                    sh_te[nxt][t0] = (1.f - svp) * sh_te[cur][t0] + svp * sh_h[cur][t0];
                    o_out[((size_t)t * BB + b) * HH + t0] = nh;
                } else {
                    float m = wx + wh;
                    sh_modin[t0 - HH] = m > 0.f ? m : 0.f;
                }
            }
        }
        __syncthreads();

        // ---- B: mod_i + dU/tE register update + fused einsum ----
        {
            float macc = 0.f;
            #pragma unroll
            for (int e = 0; e < 4; ++e) {
                const float4 m4 = m2h4[i * 16 + qq * 4 + e];
                const float4 mi = *(const float4*)&sh_modin[qq * 16 + e * 4];
                macc += m4.x*mi.x + m4.y*mi.y + m4.z*mi.z + m4.w*mi.w;
            }
            macc += __shfl_xor(macc, 1, 4);
            macc += __shfl_xor(macc, 2, 4);
            const float modi = macc;
            const float nhi  = sh_h[nxt][i];
            const float ntei = sh_te[nxt][i];
            float acc = 0.f;

#define UPDC(cc, TE) { \
            const float4 raV = raS4[(cc) * 1024 + t0]; \
            const float4 sUV = sUS4[(cc) * 1024 + t0]; \
            const float4 sEV = sES4[(cc) * 1024 + t0]; \
            const float4 hiV = hiS4[(cc) * 1024 + t0]; \
            const float4 loV = loS4[(cc) * 1024 + t0]; \
            const int j0 = (cc) * 16 + qq * 4; \
            const float4 teo = *(const float4*)&sh_te[cur][j0]; \
            const float4 ho  = *(const float4*)&sh_h[cur][j0]; \
            const float4 hn  = *(const float4*)&sh_h[nxt][j0]; \
            float4 DU = duR[cc]; \
            { float ev = (1.f-sEV.x)*TE.x + sEV.x*(nhi*teo.x - ntei*ho.x); \
              float dd = (1.f-sUV.x)*DU.x + sUV.x*modi*ev; \
              dd = fminf(dd, hiV.x); dd = fmaxf(dd, loV.x); \
              TE.x = ev; DU.x = dd; acc += raV.x*dd*hn.x; } \
            { float ev = (1.f-sEV.y)*TE.y + sEV.y*(nhi*teo.y - ntei*ho.y); \
              float dd = (1.f-sUV.y)*DU.y + sUV.y*modi*ev; \
              dd = fminf(dd, hiV.y); dd = fmaxf(dd, loV.y); \
              TE.y = ev; DU.y = dd; acc += raV.y*dd*hn.y; } \
            { float ev = (1.f-sEV.z)*TE.z + sEV.z*(nhi*teo.z - ntei*ho.z); \
              float dd = (1.f-sUV.z)*DU.z + sUV.z*modi*ev; \
              dd = fminf(dd, hiV.z); dd = fmaxf(dd, loV.z); \
              TE.z = ev; DU.z = dd; acc += raV.z*dd*hn.z; } \
            { float ev = (1.f-sEV.w)*TE.w + sEV.w*(nhi*teo.w - ntei*ho.w); \
              float dd = (1.f-sUV.w)*DU.w + sUV.w*modi*ev; \
              dd = fminf(dd, hiV.w); dd = fmaxf(dd, loV.w); \
              TE.w = ev; DU.w = dd; acc += raV.w*dd*hn.w; } \
            duR[cc] = DU; }

            #pragma unroll
            for (int c = 0; c < NREG_TE; ++c) { UPDC(c, teR[c]); }
            #pragma unroll
            for (int c2 = 0; c2 < NLDS_TE; ++c2) {
                float4 TE = tE_lds[c2 * 1024 + t0];
                UPDC(NREG_TE + c2, TE);
                tE_lds[c2 * 1024 + t0] = TE;
            }
#undef UPDC

            acc += __shfl_xor(acc, 1, 4);
            acc += __shfl_xor(acc, 2, 4);
            if (qq == 0) sh_s[i] = acc;
        }
        // no sync here: next A1 only reads sh_h[nxt] (stable) and writes
        // sh_red, whose readers (A2) are behind the A1->A2 sync.
    }

    __syncthreads();
    // ---- final outputs: T even -> final h/te in parity 0 ----
    if (t0 < HH) {
        o_v[(size_t)b * HH + t0]  = sh_v[t0];
        o_h[(size_t)b * HH + t0]  = sh_h[0][t0];
        o_te[(size_t)b * HH + t0] = sh_te[0][t0];
    }
    float4* o_dUv = (float4*)o_dU;
    float4* o_tEv = (float4*)o_tE;
    #pragma unroll
    for (int c = 0; c < 16; ++c) o_dUv[sbase + c * 4] = duR[c];
    #pragma unroll
    for (int c = 0; c < NREG_TE; ++c) o_tEv[sbase + c * 4] = teR[c];
    #pragma unroll
    for (int c2 = 0; c2 < NLDS_TE; ++c2)
        o_tEv[sbase + (NREG_TE + c2) * 4] = tE_lds[c2 * 1024 + t0];
}

extern "C" void kernel_launch(void* const* d_in, const int* in_sizes, int n_in,
                              void* d_out, int out_size, void* d_ws, size_t ws_size,
                              hipStream_t stream)
{
    const float* x     = (const float*)d_in[0];
    const float* h0    = (const float*)d_in[1];
    const float* v0    = (const float*)d_in[2];
    const float* dU0   = (const float*)d_in[3];
    const float* te0   = (const float*)d_in[4];
    const float* tE0   = (const float*)d_in[5];
    const float* x2h_w = (const float*)d_in[6];
    const float* x2h_b = (const float*)d_in[7];
    const float* h2h_w = (const float*)d_in[8];
    const float* h2h_b = (const float*)d_in[9];
    const float* lnx_g = (const float*)d_in[10];
    const float* lnx_b = (const float*)d_in[11];
    const float* lnh_g = (const float*)d_in[12];
    const float* lnh_b = (const float*)d_in[13];
    const float* alpha = (const float*)d_in[14];
    const float* mod2h = (const float*)d_in[15];
    const float* tau_v = (const float*)d_in[16];
    const float* tau_U = (const float*)d_in[17];
    const float* tau_E = (const float*)d_in[18];

    float* out  = (float*)d_out;
    float* o_v  = out;
    float* o_h  = out + 16384;
    float* o_dU = out + 32768;
    float* o_te = out + 4227072;
    float* o_tE = out + 4243456;
    float* o_out= out + 8437760;

    float* w = (float*)d_ws;
    float* Wx  = w;  w += (size_t)T_STEPS * BB * HR;
    float* ra  = w;  w += HH * HH;
    float* sU  = w;  w += HH * HH;
    float* sE  = w;  w += HH * HH;
    float* hi  = w;  w += HH * HH;
    float* lo  = w;  w += HH * HH;
    float* sv  = w;  w += 256;

    k_init_const<<<256, 256, 0, stream>>>(alpha, tau_U, tau_E, tau_v, h2h_w,
                                          ra, sU, sE, hi, lo, sv);
    k_wx<<<T_STEPS * BB, HR, 0, stream>>>(x, x2h_w, x2h_b, lnx_g, lnx_b, Wx);
    k_batch<<<BB, 1024, 0, stream>>>(dU0, tE0, h0, v0, te0, Wx,
                                     h2h_w, h2h_b, lnh_g, lnh_b, sv, mod2h,
                                     ra, sU, sE, hi, lo,
                                     o_v, o_h, o_dU, o_te, o_tE, o_out);
}